// Round 13
// baseline (155.280 us; speedup 1.0000x reference)
//
#include <hip/hip_runtime.h>

#define LN 1024
#define FF 128
#define HH 128
#define CC 10
#define DD 34314
#define OFF_W0 0
#define OFF_B0 16384
#define OFF_W1 16512
#define OFF_B1 32896
#define OFF_W2 33024
#define OFF_B2 34304

__global__ void init_delta(float* delta) { *delta = 0.f; }

__device__ __forceinline__ float invmut(const float* h, int node, int par) {
    return 1.f / fmaxf(fabsf(h[node] - h[par]), 1e-7f);
}
__device__ __forceinline__ float sgprf(float v) {
    return __uint_as_float(__builtin_amdgcn_readfirstlane(__float_as_uint(v)));
}

// 22 streams for level-7 subtree s: R[0..7] = path l7..root, R[8..9] = level-8,
// R[10..13] = level-9, R[14..21] = 8 leaves. wgt[r] = owner-gated 1/mut (0 if not owner).
__device__ __forceinline__ void setup22(const float* W, const float* hts, int s,
                                        const float** R, float* wgt) {
    int path[8];
    path[0] = 127 + s;
#pragma unroll
    for (int k = 1; k < 8; ++k) path[k] = (path[k - 1] - 1) >> 1;   // path[7] = 0
#pragma unroll
    for (int k = 0; k < 8; ++k) R[k] = W + (size_t)path[k] * DD;
    const int l8 = 255 + 2 * s;
    R[8] = W + (size_t)l8 * DD;
    R[9] = W + (size_t)(l8 + 1) * DD;
    const int l9 = 511 + 4 * s;
#pragma unroll
    for (int j = 0; j < 4; ++j) R[10 + j] = W + (size_t)(l9 + j) * DD;
    const int lf = 1023 + 8 * s;
#pragma unroll
    for (int q = 0; q < 8; ++q) R[14 + q] = W + (size_t)(lf + q) * DD;

    wgt[0] = sgprf(invmut(hts, path[0], path[1]));                  // unique per s
#pragma unroll
    for (int k = 1; k < 7; ++k)
        wgt[k] = sgprf(((s & ((1 << k) - 1)) == 0) ? invmut(hts, path[k], path[k + 1]) : 0.f);
    wgt[7] = 0.f;                                                   // root: squares separately
    wgt[8] = sgprf(invmut(hts, l8,     path[0]));
    wgt[9] = sgprf(invmut(hts, l8 + 1, path[0]));
#pragma unroll
    for (int j = 0; j < 4; ++j) wgt[10 + j] = sgprf(invmut(hts, l9 + j, l8 + (j >> 1)));
#pragma unroll
    for (int q = 0; q < 8; ++q) wgt[14 + q] = sgprf(invmut(hts, lf + q, l9 + (q >> 1)));
}

// Two-phase esum layer kernel. Block = (subtree s, col-half ch), 1024 threads.
// Tile = 16 f x 64 cols = 1024 positions. Phase A (tile t+1): sum 8 shared
// streams -> esum LDS (double-buffered) + delta. Phase B (tile t): 14 lower
// streams + esum -> tree-combine + 8-leaf matvec + delta. One barrier/tile.
// Peak live streams = 14 -> fits the 64-VGPR budget without spill (R7/R8 fix).
template <int OFFW, int OFFB>
__global__ __launch_bounds__(1024, 4) void layer2p(const float* __restrict__ W,
                                                   const float* __restrict__ invec,
                                                   const float* __restrict__ hts,
                                                   float* __restrict__ outvec,
                                                   float* __restrict__ delta_out) {
    const int bid = blockIdx.x;
    const int u   = ((bid & 7) << 5) | (bid >> 3);    // XCD-chunked bijection (256 = 8*32)
    const int s   = u >> 1;
    const int ch  = u & 1;
    const int tid = threadIdx.x, lane = tid & 63, wv = tid >> 6;
    const int ft  = tid >> 6;                         // 0..15 : f-slot within tile
    const int c   = tid & 63;                         // col within half

    const float* R[22]; float wgt[22];
    setup22(W, hts, s, R, wgt);
    const float sqm = (s == 0) ? 1.f : 0.f;

    __shared__ float esum[2][1024];   // 8 KB double-buffered shared-path sums
    __shared__ float part[8192];      // 32 KB matvec partials [q][ft][c]
    __shared__ float ins[8][128];     // 4 KB layer input per leaf
    __shared__ float ebias[64];
    __shared__ float red[16];

    { const int q = tid >> 7, f = tid & 127; ins[q][f] = invec[(8 * s + q) * 128 + f]; }

    float dacc = 0.f, sacc = 0.f;
    if (tid < 64) {                                   // path biases for this col-half
        const int gcol = ch * 64 + tid;
        float eb = 0.f;
#pragma unroll
        for (int k = 0; k < 8; ++k) {
            const float v = R[k][OFFB + gcol];
            eb += v;
            dacc += fabsf(v) * wgt[k];
            if (k == 7) sacc += v * v;
        }
        ebias[tid] = eb;
    }

    float yacc[8];
#pragma unroll
    for (int q = 0; q < 8; ++q) yacc[q] = 0.f;

    const float* S[22];
#pragma unroll
    for (int r = 0; r < 22; ++r) S[r] = R[r] + OFFW;
    const int base = ft * 128 + ch * 64 + c;          // float index of tile-0 position

    // ---- phase A, tile 0 ----
    {
        float e = 0.f;
#pragma unroll
        for (int k = 0; k < 8; ++k) {
            const float w = S[k][base];
            e += w;
            dacc += fabsf(w) * wgt[k];
            if (k == 7) sacc += w * w;
        }
        esum[0][tid] = e;
    }
    __syncthreads();

    // ---- pipelined supersteps: A(t+1) || B(t), one barrier per tile ----
#pragma unroll 1
    for (int t = 0; t < 8; ++t) {
        const int cur = t & 1;
        if (t < 7) {                                  // phase A for tile t+1
            const int ia = base + (t + 1) * 2048;     // 16 f * 128 floats per tile
            float e = 0.f;
#pragma unroll
            for (int k = 0; k < 8; ++k) {
                const float w = S[k][ia];
                e += w;
                dacc += fabsf(w) * wgt[k];
                if (k == 7) sacc += w * w;
            }
            esum[cur ^ 1][tid] = e;
        }
        {                                             // phase B for tile t
            const int ib = base + t * 2048;
            float wb[14];
#pragma unroll
            for (int j = 0; j < 14; ++j) wb[j] = S[8 + j][ib];
#pragma unroll
            for (int j = 0; j < 14; ++j) dacc += fabsf(wb[j]) * wgt[8 + j];
            const float e   = esum[cur][tid];
            const float e8a = e + wb[0], e8b = e + wb[1];
            float e9[4];
#pragma unroll
            for (int j = 0; j < 4; ++j) e9[j] = ((j >> 1) ? e8b : e8a) + wb[2 + j];
            const int f = t * 16 + ft;
#pragma unroll
            for (int q = 0; q < 8; ++q)
                yacc[q] += ins[q][f] * (e9[q >> 1] + wb[6 + q]);
        }
        __syncthreads();
    }

    // ---- reduce partials across 16 f-slots + leaf biases + relu + store ----
#pragma unroll
    for (int q = 0; q < 8; ++q) part[q * 1024 + tid] = yacc[q];
    __syncthreads();
    if (tid < 512) {
        const int q = tid >> 6, col = tid & 63;       // q wave-uniform
        const int gcol = ch * 64 + col;
        const float v8 = R[8  + (q >> 2)][OFFB + gcol];
        const float v9 = R[10 + (q >> 1)][OFFB + gcol];
        const float vl = R[14 + q      ][OFFB + gcol];
        if ((q & 3) == 0) dacc += fabsf(v8) * wgt[8  + (q >> 2)];
        if ((q & 1) == 0) dacc += fabsf(v9) * wgt[10 + (q >> 1)];
        dacc += fabsf(vl) * wgt[14 + q];
        float sum = ebias[col] + v8 + v9 + vl;
#pragma unroll
        for (int g = 0; g < 16; ++g) sum += part[q * 1024 + g * 64 + col];
        outvec[(8 * s + q) * HH + gcol] = fmaxf(sum, 0.f);
    }

    float v = dacc + sacc * sqm;
    for (int o = 32; o > 0; o >>= 1) v += __shfl_down(v, o);
    if (lane == 0) red[wv] = v;
    __syncthreads();
    if (tid == 0) {
        float t = 0.f;
#pragma unroll
        for (int wq = 0; wq < 16; ++wq) t += red[wq];
        atomicAdd(delta_out, t);
    }
}

// Layer 2 + softmax + W2/b2 delta. One block per subtree (128 blocks). (R7-verified)
__global__ __launch_bounds__(1024, 4) void head_kernel(const float* __restrict__ W,
                                                       const float* __restrict__ ws_h1,
                                                       const float* __restrict__ hts,
                                                       float* __restrict__ out,
                                                       float* __restrict__ delta_out) {
    const int bid = blockIdx.x;
    const int s   = ((bid & 7) << 4) | (bid >> 3);    // 128 = 8*16
    const int tid = threadIdx.x, lane = tid & 63, wv = tid >> 6;

    const float* R[22]; float wgt[22];
    setup22(W, hts, s, R, wgt);
    const float sqm = (s == 0) ? 1.f : 0.f;

    __shared__ float ins[8][HH];
    __shared__ float lgts[8][CC];
    __shared__ float red[16];

    { const int q = tid >> 7, cq = tid & 127; ins[q][cq] = ws_h1[(8 * s + q) * HH + cq]; }
    if (tid < 8 * CC) ((float*)lgts)[tid] = 0.f;

    float dacc = 0.f, sacc = 0.f;
    __syncthreads();

    if (tid < 640) {                                  // 640 float2 = W2 region
        const int pos = tid;
        float2 w[22];
#pragma unroll
        for (int r = 0; r < 22; ++r)
            w[r] = *reinterpret_cast<const float2*>(R[r] + OFF_W2 + 2 * pos);
#pragma unroll
        for (int r = 0; r < 22; ++r)
            dacc += (fabsf(w[r].x) + fabsf(w[r].y)) * wgt[r];
        sacc += w[7].x * w[7].x + w[7].y * w[7].y;
        float ex = w[0].x, ey = w[0].y;
#pragma unroll
        for (int k = 1; k < 8; ++k) { ex += w[k].x; ey += w[k].y; }
        float e8x[2], e8y[2];
#pragma unroll
        for (int j = 0; j < 2; ++j) { e8x[j] = ex + w[8 + j].x; e8y[j] = ey + w[8 + j].y; }
        float e9x[4], e9y[4];
#pragma unroll
        for (int j = 0; j < 4; ++j) { e9x[j] = e8x[j >> 1] + w[10 + j].x; e9y[j] = e8y[j >> 1] + w[10 + j].y; }
        const int h  = pos / 5;
        const int c0 = 2 * (pos - 5 * h);
#pragma unroll
        for (int q = 0; q < 8; ++q) {
            const float tx = e9x[q >> 1] + w[14 + q].x;
            const float ty = e9y[q >> 1] + w[14 + q].y;
            const float hv = ins[q][h];
            atomicAdd(&lgts[q][c0],     hv * tx);
            atomicAdd(&lgts[q][c0 + 1], hv * ty);
        }
    }
    __syncthreads();
    if (tid < 80) {                                   // b2 effective + delta
        const int q = tid / 10, cq = tid - 10 * q;
        float eb = 0.f;
#pragma unroll
        for (int k = 0; k < 8; ++k) {
            const float v = R[k][OFF_B2 + cq];
            eb += v;
            if (q == 0) { dacc += fabsf(v) * wgt[k]; if (k == 7) sacc += v * v; }
        }
        const float v8 = R[8  + (q >> 2)][OFF_B2 + cq];
        const float v9 = R[10 + (q >> 1)][OFF_B2 + cq];
        const float vl = R[14 + q      ][OFF_B2 + cq];
        if ((q & 3) == 0) dacc += fabsf(v8) * wgt[8  + (q >> 2)];
        if ((q & 1) == 0) dacc += fabsf(v9) * wgt[10 + (q >> 1)];
        dacc += fabsf(vl) * wgt[14 + q];
        lgts[q][cq] += eb + v8 + v9 + vl;
    }
    __syncthreads();

    if (tid < 8) {
        const int q = tid;
        float mx = lgts[q][0];
#pragma unroll
        for (int cq = 1; cq < CC; ++cq) mx = fmaxf(mx, lgts[q][cq]);
        float e[CC], ssum = 0.f;
#pragma unroll
        for (int cq = 0; cq < CC; ++cq) { e[cq] = expf(lgts[q][cq] - mx); ssum += e[cq]; }
        const float inv = 1.f / ssum;
#pragma unroll
        for (int cq = 0; cq < CC; ++cq) out[(8 * s + q) * CC + cq] = e[cq] * inv;
    }

    float v = dacc + sacc * sqm;
    for (int o = 32; o > 0; o >>= 1) v += __shfl_down(v, o);
    if (lane == 0) red[wv] = v;
    __syncthreads();
    if (tid == 0) {
        float t = 0.f;
#pragma unroll
        for (int wq = 0; wq < 16; ++wq) t += red[wq];
        atomicAdd(delta_out, t);
    }
}

extern "C" void kernel_launch(void* const* d_in, const int* in_sizes, int n_in,
                              void* d_out, int out_size, void* d_ws, size_t ws_size,
                              hipStream_t stream) {
    const float* x       = (const float*)d_in[0];   // (1024, 128)
    const float* W       = (const float*)d_in[1];   // (2047, 34314)
    const float* heights = (const float*)d_in[2];   // (2047,)

    float* out   = (float*)d_out;
    float* delta = (float*)d_out + LN * CC;
    float* ws_h0 = (float*)d_ws;                    // 512 KB
    float* ws_h1 = (float*)d_ws + LN * HH;          // 512 KB

    init_delta<<<1, 1, 0, stream>>>(delta);
    layer2p<OFF_W0, OFF_B0><<<256, 1024, 0, stream>>>(W, x, heights, ws_h0, delta);
    layer2p<OFF_W1, OFF_B1><<<256, 1024, 0, stream>>>(W, ws_h0, heights, ws_h1, delta);
    head_kernel<<<128, 1024, 0, stream>>>(W, ws_h1, heights, out, delta);
}

// Round 14
// 83.349 us; speedup vs baseline: 1.8630x; 1.8630x over previous
//
#include <hip/hip_runtime.h>

#define LN 1024
#define FF 128
#define HH 128
#define CC 10
#define DD 34314
#define DD2 17157
#define CHK 2145          // float2 chunk for eff5 pass (8 chunks cover 17157)
#define OFF_W0 0
#define OFF_B0 16384
#define OFF_W1 16512
#define OFF_B1 32896
#define OFF_W2 33024
#define OFF_B2 34304

__global__ void init_delta(float* delta) { *delta = 0.f; }

__device__ __forceinline__ float invmut(const float* h, int node, int par) {
    return 1.f / fmaxf(fabsf(h[node] - h[par]), 1e-7f);
}

// ---------------- P1: eff5[n5] = sum of rows on path level5(n5) .. root ----------------
// 256 blocks = 32 level-5 nodes x 8 chunks. Fused delta for levels 0..5
// (owner-gated by n5; root contributes sum-of-squares).
__global__ __launch_bounds__(1024) void eff5_kernel(const float* __restrict__ W,
                                                    const float* __restrict__ heights,
                                                    float* __restrict__ eff,
                                                    float* __restrict__ delta_out) {
    const int bid = blockIdx.x;
    const int n5  = bid >> 3;            // 0..31
    const int ck  = bid & 7;             // chunk
    const int tid = threadIdx.x, lane = tid & 63, wv = tid >> 6;

    int p[6];
    p[0] = 31 + n5;
#pragma unroll
    for (int k = 1; k < 6; ++k) p[k] = (p[k - 1] - 1) >> 1;   // p[5] = 0 (root)

    const float2* S[6];
#pragma unroll
    for (int k = 0; k < 6; ++k) S[k] = reinterpret_cast<const float2*>(W + (size_t)p[k] * DD);
    float2* E = reinterpret_cast<float2*>(eff + (size_t)n5 * DD);

    float wgt[6];
#pragma unroll
    for (int k = 0; k < 5; ++k)
        wgt[k] = ((n5 & ((1 << k) - 1)) == 0) ? invmut(heights, p[k], p[k + 1]) : 0.f;
    wgt[5] = 0.f;                        // root: squares via sacc
    const float sqm = (n5 == 0) ? 1.f : 0.f;

    float dacc = 0.f, sacc = 0.f;
    const int lo = ck * CHK;
    const int hi = min(lo + CHK, DD2);
#pragma unroll 1
    for (int i = lo + tid; i < hi; i += 1024) {
        float ex = 0.f, ey = 0.f;
#pragma unroll
        for (int k = 0; k < 6; ++k) {
            const float2 w = S[k][i];
            ex += w.x; ey += w.y;
            dacc += (fabsf(w.x) + fabsf(w.y)) * wgt[k];
            if (k == 5) sacc += w.x * w.x + w.y * w.y;
        }
        E[i] = make_float2(ex, ey);
    }

    __shared__ float red[16];
    float v = dacc + sacc * sqm;
    for (int o = 32; o > 0; o >>= 1) v += __shfl_down(v, o);
    if (lane == 0) red[wv] = v;
    __syncthreads();
    if (tid == 0) {
        float s = 0.f;
#pragma unroll
        for (int w = 0; w < 16; ++w) s += red[w];
        atomicAdd(delta_out, s);
    }
}

// ---------------- P2: R10's proven fused kernel, 15 -> 10 streams ----------------
// Streams: E = eff5 (levels 0..5, L2-resident), P[0..2] = l8/l7/l6,
// A[0..1] = level-9 pair, B[0..3] = 4 leaves. Delta fused for levels 6..10.
__global__ __launch_bounds__(1024, 4)
__attribute__((amdgpu_waves_per_eu(4, 4)))
void fused_kernel(const float* __restrict__ W,
                  const float* __restrict__ eff,
                  const float* __restrict__ x,
                  const float* __restrict__ heights,
                  float* __restrict__ out,
                  float* __restrict__ delta_out) {
    const int bid  = blockIdx.x;
    const int m    = ((bid & 7) << 5) | (bid >> 3);   // XCD-chunked bijection (256 = 8*32)
    const int tid  = threadIdx.x;
    const int lane = tid & 63;
    const int wv   = tid >> 6;          // 0..15 : f-range [8*wv, 8*wv+8)
    const int j2   = lane;              // column pair (2*j2, 2*j2+1)

    const int l8 = 255 + m;
    const int l7 = (l8 - 1) >> 1;
    const int l6 = (l7 - 1) >> 1;
    const int l5 = (l6 - 1) >> 1;

    const float* RE = eff + (size_t)(m >> 3) * DD;
    const float* RP[3];
    RP[0] = W + (size_t)l8 * DD;
    RP[1] = W + (size_t)l7 * DD;
    RP[2] = W + (size_t)l6 * DD;
    const int n9a = 511 + 2 * m, n9b = n9a + 1;
    const float* RA[2];
    RA[0] = W + (size_t)n9a * DD;
    RA[1] = W + (size_t)n9b * DD;
    const float* RB[4];
#pragma unroll
    for (int q = 0; q < 4; ++q) RB[q] = W + (size_t)(1023 + 4 * m + q) * DD;

    float wgtP[3];
    wgtP[0] = invmut(heights, l8, l7);                       // unique per block
    wgtP[1] = ((m & 1) == 0) ? invmut(heights, l7, l6) : 0.f;
    wgtP[2] = ((m & 3) == 0) ? invmut(heights, l6, l5) : 0.f;
    float wgtA[2];
    wgtA[0] = invmut(heights, n9a, l8);
    wgtA[1] = invmut(heights, n9b, l8);
    float wgtB[4];
#pragma unroll
    for (int q = 0; q < 4; ++q)
        wgtB[q] = invmut(heights, 1023 + 4 * m + q, (q < 2) ? n9a : n9b);

    __shared__ float ins[4][HH];         // current layer input per leaf
    __shared__ float part[4][16][HH];    // matvec partials [leaf][wave][col]  (32 KB)
    __shared__ float lgts[4][CC];
    __shared__ float red[16];

    if (tid < 512) { const int q = tid >> 7, t = tid & 127; ins[q][t] = x[(4 * m + q) * FF + t]; }
    if (tid < 4 * CC) ((float*)lgts)[tid] = 0.f;

    float dacc = 0.f;
    __syncthreads();

    // ---------------- layers 0 and 1 (128 -> 128) ----------------
#pragma unroll
    for (int layer = 0; layer < 2; ++layer) {
        const int offW = layer ? OFF_W1 : OFF_W0;
        const int offB = layer ? OFF_B1 : OFF_B0;
        const float2* SE = reinterpret_cast<const float2*>(RE + offW);
        const float2* SP[3];
#pragma unroll
        for (int r = 0; r < 3; ++r) SP[r] = reinterpret_cast<const float2*>(RP[r] + offW);
        const float2* SA[2];
#pragma unroll
        for (int r = 0; r < 2; ++r) SA[r] = reinterpret_cast<const float2*>(RA[r] + offW);
        const float2* SB[4];
#pragma unroll
        for (int r = 0; r < 4; ++r) SB[r] = reinterpret_cast<const float2*>(RB[r] + offW);

        float yx[4], yy[4];
#pragma unroll
        for (int q = 0; q < 4; ++q) { yx[q] = 0.f; yy[q] = 0.f; }

#pragma unroll 2
        for (int i = 0; i < 8; ++i) {
            const int f   = (wv << 3) + i;
            const int off = (f << 6) + j2;
            const float2 we = SE[off];
            float ex = we.x, ey = we.y;
#pragma unroll
            for (int k = 0; k < 3; ++k) {
                const float2 w = SP[k][off];
                ex += w.x; ey += w.y;
                dacc += (fabsf(w.x) + fabsf(w.y)) * wgtP[k];
            }
            const float2 wa0 = SA[0][off];
            const float2 wa1 = SA[1][off];
            dacc += (fabsf(wa0.x) + fabsf(wa0.y)) * wgtA[0];
            dacc += (fabsf(wa1.x) + fabsf(wa1.y)) * wgtA[1];
#pragma unroll
            for (int q = 0; q < 4; ++q) {
                const float2 wb = SB[q][off];
                dacc += (fabsf(wb.x) + fabsf(wb.y)) * wgtB[q];
                const float2 wa = (q < 2) ? wa0 : wa1;
                const float xv = ins[q][f];
                yx[q] += xv * (ex + wa.x + wb.x);
                yy[q] += xv * (ey + wa.y + wb.y);
            }
        }
#pragma unroll
        for (int q = 0; q < 4; ++q)
            *reinterpret_cast<float2*>(&part[q][wv][2 * j2]) = make_float2(yx[q], yy[q]);
        __syncthreads();

        if (tid < 512) {
            const int q = tid >> 7, col = tid & 127;   // q uniform per wave
            const float p0 = RP[0][offB + col];
            const float p1 = RP[1][offB + col];
            const float p2 = RP[2][offB + col];
            float eb = RE[offB + col] + p0 + p1 + p2;
            if (q == 0)
                dacc += fabsf(p0) * wgtP[0] + fabsf(p1) * wgtP[1] + fabsf(p2) * wgtP[2];
            const float a0 = RA[0][offB + col];
            const float a1 = RA[1][offB + col];
            if (q == 0) dacc += fabsf(a0) * wgtA[0];
            if (q == 2) dacc += fabsf(a1) * wgtA[1];
            const float bq = RB[q][offB + col];
            dacc += fabsf(bq) * wgtB[q];
            float s = eb + ((q < 2) ? a0 : a1) + bq;
#pragma unroll
            for (int w = 0; w < 16; ++w) s += part[q][w][col];
            ins[q][col] = fmaxf(s, 0.f);
        }
        __syncthreads();
    }

    // ---------------- layer 2 (128 -> 10) ----------------
    {
        const float2* SE = reinterpret_cast<const float2*>(RE + OFF_W2);
        const float2* SP[3];
#pragma unroll
        for (int r = 0; r < 3; ++r) SP[r] = reinterpret_cast<const float2*>(RP[r] + OFF_W2);
        const float2* SA[2];
#pragma unroll
        for (int r = 0; r < 2; ++r) SA[r] = reinterpret_cast<const float2*>(RA[r] + OFF_W2);
        const float2* SB[4];
#pragma unroll
        for (int r = 0; r < 4; ++r) SB[r] = reinterpret_cast<const float2*>(RB[r] + OFF_W2);
        if (tid < 640) {                 // 640 float2 = 1280 weights per row
            const int h  = tid / 5;
            const int c0 = (tid - 5 * h) * 2;
            const float2 we = SE[tid];
            float ex = we.x, ey = we.y;
#pragma unroll
            for (int k = 0; k < 3; ++k) {
                const float2 w = SP[k][tid];
                ex += w.x; ey += w.y;
                dacc += (fabsf(w.x) + fabsf(w.y)) * wgtP[k];
            }
            const float2 wa0 = SA[0][tid];
            const float2 wa1 = SA[1][tid];
            dacc += (fabsf(wa0.x) + fabsf(wa0.y)) * wgtA[0];
            dacc += (fabsf(wa1.x) + fabsf(wa1.y)) * wgtA[1];
#pragma unroll
            for (int q = 0; q < 4; ++q) {
                const float2 wb = SB[q][tid];
                dacc += (fabsf(wb.x) + fabsf(wb.y)) * wgtB[q];
                const float2 wa = (q < 2) ? wa0 : wa1;
                const float hv = ins[q][h];
                atomicAdd(&lgts[q][c0],     hv * (ex + wa.x + wb.x));
                atomicAdd(&lgts[q][c0 + 1], hv * (ey + wa.y + wb.y));
            }
        }
        __syncthreads();
        if (tid < CC) {
            const float p0 = RP[0][OFF_B2 + tid];
            const float p1 = RP[1][OFF_B2 + tid];
            const float p2 = RP[2][OFF_B2 + tid];
            float eb = RE[OFF_B2 + tid] + p0 + p1 + p2;
            dacc += fabsf(p0) * wgtP[0] + fabsf(p1) * wgtP[1] + fabsf(p2) * wgtP[2];
            const float a0 = RA[0][OFF_B2 + tid];
            const float a1 = RA[1][OFF_B2 + tid];
            dacc += fabsf(a0) * wgtA[0] + fabsf(a1) * wgtA[1];
#pragma unroll
            for (int q = 0; q < 4; ++q) {
                const float bq = RB[q][OFF_B2 + tid];
                dacc += fabsf(bq) * wgtB[q];
                lgts[q][tid] += eb + ((q < 2) ? a0 : a1) + bq;
            }
        }
        __syncthreads();
    }

    // ---------------- softmax (one thread per leaf) ----------------
    if (tid < 4) {
        const int q = tid;
        float mx = lgts[q][0];
#pragma unroll
        for (int c = 1; c < CC; ++c) mx = fmaxf(mx, lgts[q][c]);
        float e[CC], s = 0.f;
#pragma unroll
        for (int c = 0; c < CC; ++c) { e[c] = expf(lgts[q][c] - mx); s += e[c]; }
        const float inv = 1.f / s;
#pragma unroll
        for (int c = 0; c < CC; ++c) out[(4 * m + q) * CC + c] = e[c] * inv;
    }

    // ---------------- delta reduce ----------------
    float v = dacc;
    for (int o = 32; o > 0; o >>= 1) v += __shfl_down(v, o);
    if (lane == 0) red[wv] = v;
    __syncthreads();
    if (tid == 0) {
        float s = 0.f;
#pragma unroll
        for (int w = 0; w < 16; ++w) s += red[w];
        atomicAdd(delta_out, s);
    }
}

extern "C" void kernel_launch(void* const* d_in, const int* in_sizes, int n_in,
                              void* d_out, int out_size, void* d_ws, size_t ws_size,
                              hipStream_t stream) {
    const float* x       = (const float*)d_in[0];   // (1024, 128)
    const float* W       = (const float*)d_in[1];   // (2047, 34314)
    const float* heights = (const float*)d_in[2];   // (2047,)

    float* out   = (float*)d_out;
    float* delta = (float*)d_out + LN * CC;
    float* eff   = (float*)d_ws;                    // 32 * 34314 * 4 B = 4.4 MB

    init_delta<<<1, 1, 0, stream>>>(delta);
    eff5_kernel<<<256, 1024, 0, stream>>>(W, heights, eff, delta);
    fused_kernel<<<256, 1024, 0, stream>>>(W, eff, x, heights, out, delta);
}